// Round 8
// baseline (4849.249 us; speedup 1.0000x reference)
//
#include <hip/hip_runtime.h>
#include <cstdint>
#include <cstddef>

// ---------------------------------------------------------------------------
// BsPINN forward, int8 dual-fixed-point MFMA (round 8).
// R7 post-mortem: DMA staging + n-fast grid exploded FETCH 270MB->1.6GB
// (XCD-replicated A + uncached DMA gather). Both reverted to R6's green
// config (explicit staging, m-fast grid, 1019us).
// R8 single change: software-pipelined staging (prefetch k-tile t+1 into
// regs before MFMA of tile t) + __launch_bounds__(256,4) VGPR cap.
// Scheme (proven R6, absmax 4.9e-4):
//   h = H1*2^-6 + H2*2^-13 (i8 pair), w = W1*2^-10 + W2*2^-17 (i8 pair)
//   preact = (sum H1W1)*2^-16 + (sum H1W2 + H2W1)*2^-23 + bias
//   3 x mfma_i32_16x16x64_i8 per K=64; i32 accum exact (<8M << 2^31).
// ---------------------------------------------------------------------------

typedef int          intx4   __attribute__((ext_vector_type(4)));
typedef float        floatx8 __attribute__((ext_vector_type(8)));
typedef signed char  i8x8    __attribute__((ext_vector_type(8)));

__device__ __forceinline__ float tanh_fast(float x) {
    float e = __expf(2.0f * x);
    return 1.0f - 2.0f / (e + 1.0f);
}
// h in (-1,1) -> H1 = rne(h*64), H2 = rne((h-H1/64)*8192); both in [-64,64].
__device__ __forceinline__ void quant_h(float o, signed char& q1, signed char& q2) {
    float a = rintf(o * 64.0f);
    float r = fmaf(a, -0.015625f, o);          // o - a/64, exact
    q1 = (signed char)(int)a;
    q2 = (signed char)(int)rintf(r * 8192.0f);
}
// |w|<=0.0542 -> W1 = rne(w*1024) in [-56,56], W2 = rne((w-W1/1024)*2^17).
__device__ __forceinline__ void quant_w(float v, signed char& q1, signed char& q2) {
    float a = rintf(v * 1024.0f);
    float r = fmaf(a, -0.0009765625f, v);      // v - a/1024, exact
    q1 = (signed char)(int)a;
    q2 = (signed char)(int)rintf(r * 131072.0f);
}

// ---------------------------------------------------------------------------
// Weight transpose + int8 hi/lo quant: fp32 W[K][N] -> i8 W1q/W2q[N][K].
// ---------------------------------------------------------------------------
__global__ __launch_bounds__(256)
void transposeQ(const float* __restrict__ W,
                signed char* __restrict__ W1q, signed char* __restrict__ W2q) {
    __shared__ float tile[32][33];
    const int tx = threadIdx.x & 31;
    const int ty = threadIdx.x >> 5;     // 0..7
    #pragma unroll
    for (int j = 0; j < 4; ++j) {
        int r = ty + j * 8;
        tile[r][tx] = W[(size_t)(blockIdx.y * 32 + r) * 1024 + blockIdx.x * 32 + tx];
    }
    __syncthreads();
    #pragma unroll
    for (int j = 0; j < 4; ++j) {
        int r = ty + j * 8;
        float v = tile[tx][r];
        signed char q1, q2;
        quant_w(v, q1, q2);
        const size_t o = (size_t)(blockIdx.x * 32 + r) * 1024 + blockIdx.y * 32 + tx;
        W1q[o] = q1;
        W2q[o] = q2;
    }
}

// ---------------------------------------------------------------------------
// Layer 0 (fp32 in): h0 = tanh(xa*W0[0][:] + xb*W0[1][:] + b0) -> i8 pair.
// ---------------------------------------------------------------------------
__global__ __launch_bounds__(256)
void layer0_kernel(const float* __restrict__ X, const float* __restrict__ W0,
                   const float* __restrict__ b0,
                   signed char* __restrict__ H1, signed char* __restrict__ H2) {
    const int idx = blockIdx.x * 256 + threadIdx.x;
    const int row = idx >> 7;
    const int j0  = (idx & 127) << 3;
    const float x0 = X[row * 2 + 0];
    const float x1 = X[row * 2 + 1];
    const float xa = x0 * 0.31830988618379067f - 1.0f;   // x0/pi - 1
    const float xb = 2.0f * x1 - 1.0f;
    floatx8 wa = *(const floatx8*)(W0 + j0);
    floatx8 wb = *(const floatx8*)(W0 + 1024 + j0);
    floatx8 bb = *(const floatx8*)(b0 + j0);
    i8x8 o1, o2;
    #pragma unroll
    for (int j = 0; j < 8; ++j) {
        float v = fmaf(xa, wa[j], fmaf(xb, wb[j], bb[j]));
        float o = tanh_fast(v);
        signed char q1, q2;
        quant_h(o, q1, q2);
        o1[j] = q1;
        o2[j] = q2;
    }
    const size_t off = (size_t)row * 1024 + j0;
    *(i8x8*)(H1 + off) = o1;
    *(i8x8*)(H2 + off) = o2;
}

// ---------------------------------------------------------------------------
// GEMM + bias + tanh, i8 dual-fixed-point, software-pipelined staging.
// Grid (m-fast, n=8 slow) — R6's proven cache-friendly order.
// 128x128 tile, BK=64, 4 waves (2x2), 4x4 16x16x64 frags, 3 MFMAs/frag/kiter.
// Pipeline: regs hold tile t; per iter: barrier, ds_write t, barrier,
// issue global loads t+1 (overlap MFMA), ds_read+MFMA on t.
// ---------------------------------------------------------------------------
__global__ __launch_bounds__(256, 4)
void gemm_tanh_i8(const signed char* __restrict__ A1, const signed char* __restrict__ A2,
                  const signed char* __restrict__ B1, const signed char* __restrict__ B2,
                  const float* __restrict__ bias,
                  signed char* __restrict__ C1, signed char* __restrict__ C2, int KB) {
    __shared__ signed char As1[128 * 64];
    __shared__ signed char As2[128 * 64];
    __shared__ signed char Bs1[128 * 64];
    __shared__ signed char Bs2[128 * 64];

    const int tid  = threadIdx.x;
    const int lane = tid & 63;
    const int wave = tid >> 6;
    const int m0 = blockIdx.x * 128;          // m fast (R6 order)
    const int n0 = blockIdx.y * 128;
    const int kbeg   = (n0 / KB) * KB;
    const int kiters = KB >> 6;
    const int wm = (wave & 1) << 6;
    const int wn = (wave >> 1) << 6;
    const int r = lane & 15;
    const int q = lane >> 4;

    // Per-thread staging geometry (fixed across k-iters).
    const int rowA0 = tid >> 2;               // slot tid       -> rows 0..63
    const int rowA1 = (256 + tid) >> 2;       // slot 256+tid   -> rows 64..127
    const int seg   = (tid & 3) << 4;         // 16B segment in 64B row
    const size_t gA0 = (size_t)(m0 + rowA0) * 1024 + kbeg + seg;
    const size_t gA1 = (size_t)(m0 + rowA1) * 1024 + kbeg + seg;
    const size_t gB0 = (size_t)(n0 + rowA0) * 1024 + kbeg + seg;
    const size_t gB1 = (size_t)(n0 + rowA1) * 1024 + kbeg + seg;
    const int ldsOff0 = tid * 16;
    const int ldsOff1 = (256 + tid) * 16;

    intx4 accM[4][4], accX[4][4];
    #pragma unroll
    for (int i = 0; i < 4; ++i)
        #pragma unroll
        for (int j = 0; j < 4; ++j) {
            accM[i][j] = intx4{0, 0, 0, 0};
            accX[i][j] = intx4{0, 0, 0, 0};
        }

    // Prologue: load k-tile 0 into regs.
    intx4 va1[2], va2[2], vb1[2], vb2[2];
    va1[0] = *(const intx4*)(A1 + gA0);  va1[1] = *(const intx4*)(A1 + gA1);
    va2[0] = *(const intx4*)(A2 + gA0);  va2[1] = *(const intx4*)(A2 + gA1);
    vb1[0] = *(const intx4*)(B1 + gB0);  vb1[1] = *(const intx4*)(B1 + gB1);
    vb2[0] = *(const intx4*)(B2 + gB0);  vb2[1] = *(const intx4*)(B2 + gB1);

    for (int t = 0; t < kiters; ++t) {
        __syncthreads();                      // prior iter's ds_reads done
        *(intx4*)(As1 + ldsOff0) = va1[0];  *(intx4*)(As1 + ldsOff1) = va1[1];
        *(intx4*)(As2 + ldsOff0) = va2[0];  *(intx4*)(As2 + ldsOff1) = va2[1];
        *(intx4*)(Bs1 + ldsOff0) = vb1[0];  *(intx4*)(Bs1 + ldsOff1) = vb1[1];
        *(intx4*)(Bs2 + ldsOff0) = vb2[0];  *(intx4*)(Bs2 + ldsOff1) = vb2[1];
        __syncthreads();                      // tile t visible

        // Prefetch tile t+1 (overlaps the MFMA section below).
        if (t + 1 < kiters) {
            const size_t d = (size_t)(t + 1) << 6;
            va1[0] = *(const intx4*)(A1 + gA0 + d);  va1[1] = *(const intx4*)(A1 + gA1 + d);
            va2[0] = *(const intx4*)(A2 + gA0 + d);  va2[1] = *(const intx4*)(A2 + gA1 + d);
            vb1[0] = *(const intx4*)(B1 + gB0 + d);  vb1[1] = *(const intx4*)(B1 + gB1 + d);
            vb2[0] = *(const intx4*)(B2 + gB0 + d);  vb2[1] = *(const intx4*)(B2 + gB1 + d);
        }

        intx4 a1[4], b1[4];
        #pragma unroll
        for (int i = 0; i < 4; ++i) {
            a1[i] = *(const intx4*)(As1 + (wm + i * 16 + r) * 64 + q * 16);
            b1[i] = *(const intx4*)(Bs1 + (wn + i * 16 + r) * 64 + q * 16);
        }
        #pragma unroll
        for (int i = 0; i < 4; ++i)
            #pragma unroll
            for (int j = 0; j < 4; ++j)
                accM[i][j] = __builtin_amdgcn_mfma_i32_16x16x64_i8(a1[i], b1[j], accM[i][j], 0, 0, 0);
        intx4 a2[4];
        #pragma unroll
        for (int i = 0; i < 4; ++i)
            a2[i] = *(const intx4*)(As2 + (wm + i * 16 + r) * 64 + q * 16);
        #pragma unroll
        for (int i = 0; i < 4; ++i)
            #pragma unroll
            for (int j = 0; j < 4; ++j)
                accX[i][j] = __builtin_amdgcn_mfma_i32_16x16x64_i8(a2[i], b1[j], accX[i][j], 0, 0, 0);
        intx4 b2[4];
        #pragma unroll
        for (int i = 0; i < 4; ++i)
            b2[i] = *(const intx4*)(Bs2 + (wn + i * 16 + r) * 64 + q * 16);
        #pragma unroll
        for (int i = 0; i < 4; ++i)
            #pragma unroll
            for (int j = 0; j < 4; ++j)
                accX[i][j] = __builtin_amdgcn_mfma_i32_16x16x64_i8(a1[i], b2[j], accX[i][j], 0, 0, 0);
    }

    // Epilogue. C/D layout: col=lane&15, row=(lane>>4)*4+reg.
    #pragma unroll
    for (int j = 0; j < 4; ++j) {
        const int col = n0 + wn + j * 16 + r;
        const float bv = bias[col];
        #pragma unroll
        for (int i = 0; i < 4; ++i) {
            const int row0 = m0 + wm + i * 16 + q * 4;
            #pragma unroll
            for (int rr = 0; rr < 4; ++rr) {
                float pre = fmaf((float)accM[i][j][rr], 0x1p-16f,
                            fmaf((float)accX[i][j][rr], 0x1p-23f, bv));
                float o = tanh_fast(pre);
                signed char q1, q2;
                quant_h(o, q1, q2);
                const size_t idx = (size_t)(row0 + rr) * 1024 + col;
                C1[idx] = q1;
                C2[idx] = q2;
            }
        }
    }
}

// ---------------------------------------------------------------------------
// Final: out[row] = h3[row,:] . W_last + b_last; h3 = H1*2^-6 + H2*2^-13.
// ---------------------------------------------------------------------------
__global__ __launch_bounds__(256)
void final_kernel(const signed char* __restrict__ H1, const signed char* __restrict__ H2,
                  const float* __restrict__ Wl, const float* __restrict__ bl,
                  float* __restrict__ out) {
    const int lane = threadIdx.x & 63;
    const int wave = threadIdx.x >> 6;
    const int row  = blockIdx.x * 4 + wave;
    const size_t base = (size_t)row * 1024;
    float s = 0.0f;
    #pragma unroll
    for (int c = 0; c < 2; ++c) {
        const int e = c * 512 + lane * 8;
        i8x8 h1 = *(const i8x8*)(H1 + base + e);
        i8x8 h2 = *(const i8x8*)(H2 + base + e);
        floatx8 wv = *(const floatx8*)(Wl + e);
        #pragma unroll
        for (int j = 0; j < 8; ++j) {
            float h = fmaf((float)h2[j], 0x1p-13f, (float)h1[j] * 0x1p-6f);
            s = fmaf(h, wv[j], s);
        }
    }
    #pragma unroll
    for (int off = 32; off > 0; off >>= 1) s += __shfl_down(s, off);
    if (lane == 0) out[row] = s + bl[0];
}

// ---------------------------------------------------------------------------
extern "C" void kernel_launch(void* const* d_in, const int* in_sizes, int n_in,
                              void* d_out, int out_size, void* d_ws, size_t ws_size,
                              hipStream_t stream) {
    const float* X  = (const float*)d_in[0];
    const float* W0 = (const float*)d_in[1];
    const float* b0 = (const float*)d_in[2];
    const float* W1 = (const float*)d_in[3];
    const float* b1 = (const float*)d_in[4];
    const float* W2 = (const float*)d_in[5];
    const float* b2 = (const float*)d_in[6];
    const float* W3 = (const float*)d_in[7];
    const float* b3 = (const float*)d_in[8];
    const float* Wl = (const float*)d_in[9];
    const float* bl = (const float*)d_in[10];
    float* out = (float*)d_out;

    const int Nrows = in_sizes[0] / 2;                 // 65536
    const size_t WT = 1024 * 1024;                     // bytes per i8 weight plane
    const size_t wt_bytes = 6 * WT;                    // 6 MiB
    const size_t slack = 512;

    int R = 0;
    const int Rcap = Nrows < 32768 ? Nrows : 32768;
    for (int r = Rcap; r >= 128; r >>= 1)
        if ((size_t)4 * r * 1024 + wt_bytes + slack <= ws_size) { R = r; break; }
    if (!R) return;

    signed char* wsp  = (signed char*)d_ws;
    signed char* Wt1a = wsp;            signed char* Wt1b = Wt1a + WT;
    signed char* Wt2a = Wt1b + WT;      signed char* Wt2b = Wt2a + WT;
    signed char* Wt3a = Wt2b + WT;      signed char* Wt3b = Wt3a + WT;
    const size_t plane = (size_t)R * 1024;
    signed char* P0a = Wt3b + WT;       signed char* P0b = P0a + plane;
    signed char* P1a = P0b + plane;     signed char* P1b = P1a + plane;

    const dim3 tb(256);
    transposeQ<<<dim3(32, 32), tb, 0, stream>>>(W1, Wt1a, Wt1b);
    transposeQ<<<dim3(32, 32), tb, 0, stream>>>(W2, Wt2a, Wt2b);
    transposeQ<<<dim3(32, 32), tb, 0, stream>>>(W3, Wt3a, Wt3b);

    const int nchunks = Nrows / R;
    for (int c = 0; c < nchunks; ++c) {
        const float* Xc = X + (size_t)c * R * 2;
        float* outc = out + (size_t)c * R;

        layer0_kernel<<<R / 2, tb, 0, stream>>>(Xc, W0, b0, P0a, P0b);

        const dim3 gg(R / 128, 8);                    // m fast (R6 order)
        gemm_tanh_i8<<<gg, tb, 0, stream>>>(P0a, P0b, Wt1a, Wt1b, b1, P1a, P1b, 1024);
        gemm_tanh_i8<<<gg, tb, 0, stream>>>(P1a, P1b, Wt2a, Wt2b, b2, P0a, P0b, 512);
        gemm_tanh_i8<<<gg, tb, 0, stream>>>(P0a, P0b, Wt3a, Wt3b, b3, P1a, P1b, 256);

        final_kernel<<<R / 4, tb, 0, stream>>>(P1a, P1b, Wl, bl, outc);
    }
}

// Round 9
// 1374.457 us; speedup vs baseline: 3.5281x; 3.5281x over previous
//
#include <hip/hip_runtime.h>
#include <cstdint>
#include <cstddef>

// ---------------------------------------------------------------------------
// BsPINN forward, int8 dual-fixed-point MFMA (round 9).
// R7/R8 post-mortem: __launch_bounds__(256,4) forced VGPR<=64+spills ->
// 3.7 GB scratch WRITE traffic (the real regression cause both rounds).
// R9 structural change vs green R6: NO LDS, NO barriers. Both A and B are
// [row][K] row-major and the 16x16x64 i8 fragment is 16 contiguous bytes
// per lane (row = wm+i*16+(lane&15), k += (lane>>4)*16) -> load fragments
// DIRECTLY from global. L1 absorbs intra-block row reuse; L2/LLC serves the
// 2 MB weight planes to all blocks. No barrier drain; compiler pipelines
// loads across k-iters freely.
// Scheme (proven R6, absmax 4.9e-4):
//   h = H1*2^-6 + H2*2^-13 (i8 pair), w = W1*2^-10 + W2*2^-17 (i8 pair)
//   preact = (sum H1W1)*2^-16 + (sum H1W2 + H2W1)*2^-23 + bias
//   3 x mfma_i32_16x16x64_i8 per K=64; i32 accum exact (<8M << 2^31).
// ---------------------------------------------------------------------------

typedef int          intx4   __attribute__((ext_vector_type(4)));
typedef float        floatx8 __attribute__((ext_vector_type(8)));
typedef signed char  i8x8    __attribute__((ext_vector_type(8)));

__device__ __forceinline__ float tanh_fast(float x) {
    float e = __expf(2.0f * x);
    return 1.0f - 2.0f / (e + 1.0f);
}
// h in (-1,1) -> H1 = rne(h*64), H2 = rne((h-H1/64)*8192); both in [-64,64].
__device__ __forceinline__ void quant_h(float o, signed char& q1, signed char& q2) {
    float a = rintf(o * 64.0f);
    float r = fmaf(a, -0.015625f, o);          // o - a/64, exact
    q1 = (signed char)(int)a;
    q2 = (signed char)(int)rintf(r * 8192.0f);
}
// |w|<=0.0542 -> W1 = rne(w*1024) in [-56,56], W2 = rne((w-W1/1024)*2^17).
__device__ __forceinline__ void quant_w(float v, signed char& q1, signed char& q2) {
    float a = rintf(v * 1024.0f);
    float r = fmaf(a, -0.0009765625f, v);      // v - a/1024, exact
    q1 = (signed char)(int)a;
    q2 = (signed char)(int)rintf(r * 131072.0f);
}

// ---------------------------------------------------------------------------
// Weight transpose + int8 hi/lo quant: fp32 W[K][N] -> i8 W1q/W2q[N][K].
// ---------------------------------------------------------------------------
__global__ __launch_bounds__(256)
void transposeQ(const float* __restrict__ W,
                signed char* __restrict__ W1q, signed char* __restrict__ W2q) {
    __shared__ float tile[32][33];
    const int tx = threadIdx.x & 31;
    const int ty = threadIdx.x >> 5;     // 0..7
    #pragma unroll
    for (int j = 0; j < 4; ++j) {
        int r = ty + j * 8;
        tile[r][tx] = W[(size_t)(blockIdx.y * 32 + r) * 1024 + blockIdx.x * 32 + tx];
    }
    __syncthreads();
    #pragma unroll
    for (int j = 0; j < 4; ++j) {
        int r = ty + j * 8;
        float v = tile[tx][r];
        signed char q1, q2;
        quant_w(v, q1, q2);
        const size_t o = (size_t)(blockIdx.x * 32 + r) * 1024 + blockIdx.y * 32 + tx;
        W1q[o] = q1;
        W2q[o] = q2;
    }
}

// ---------------------------------------------------------------------------
// Layer 0 (fp32 in): h0 = tanh(xa*W0[0][:] + xb*W0[1][:] + b0) -> i8 pair.
// ---------------------------------------------------------------------------
__global__ __launch_bounds__(256)
void layer0_kernel(const float* __restrict__ X, const float* __restrict__ W0,
                   const float* __restrict__ b0,
                   signed char* __restrict__ H1, signed char* __restrict__ H2) {
    const int idx = blockIdx.x * 256 + threadIdx.x;
    const int row = idx >> 7;
    const int j0  = (idx & 127) << 3;
    const float x0 = X[row * 2 + 0];
    const float x1 = X[row * 2 + 1];
    const float xa = x0 * 0.31830988618379067f - 1.0f;   // x0/pi - 1
    const float xb = 2.0f * x1 - 1.0f;
    floatx8 wa = *(const floatx8*)(W0 + j0);
    floatx8 wb = *(const floatx8*)(W0 + 1024 + j0);
    floatx8 bb = *(const floatx8*)(b0 + j0);
    i8x8 o1, o2;
    #pragma unroll
    for (int j = 0; j < 8; ++j) {
        float v = fmaf(xa, wa[j], fmaf(xb, wb[j], bb[j]));
        float o = tanh_fast(v);
        signed char q1, q2;
        quant_h(o, q1, q2);
        o1[j] = q1;
        o2[j] = q2;
    }
    const size_t off = (size_t)row * 1024 + j0;
    *(i8x8*)(H1 + off) = o1;
    *(i8x8*)(H2 + off) = o2;
}

// ---------------------------------------------------------------------------
// GEMM + bias + tanh, i8 dual-fixed-point, LDS-FREE.
// Fragments loaded directly from global: A rows m0+wm+i*16+r, B rows
// n0+wn+j*16+r, 16B at k + q*16. No __syncthreads anywhere.
// Grid (m-fast, n=8 slow). 128x128 tile, 4 waves (2x2), 4x4 frags,
// 3 MFMAs/frag per K=64.
// ---------------------------------------------------------------------------
__global__ __launch_bounds__(256)
void gemm_tanh_i8(const signed char* __restrict__ A1, const signed char* __restrict__ A2,
                  const signed char* __restrict__ B1, const signed char* __restrict__ B2,
                  const float* __restrict__ bias,
                  signed char* __restrict__ C1, signed char* __restrict__ C2, int KB) {
    const int tid  = threadIdx.x;
    const int lane = tid & 63;
    const int wave = tid >> 6;
    const int m0 = blockIdx.x * 128;          // m fast
    const int n0 = blockIdx.y * 128;
    const int kbeg   = (n0 / KB) * KB;
    const int kiters = KB >> 6;
    const int wm = (wave & 1) << 6;
    const int wn = (wave >> 1) << 6;
    const int r = lane & 15;
    const int q = lane >> 4;

    // Per-lane fragment base pointers (row * 1024 + kbeg + q*16).
    const size_t aoff = (size_t)(m0 + wm + r) * 1024 + kbeg + q * 16;
    const size_t boff = (size_t)(n0 + wn + r) * 1024 + kbeg + q * 16;
    const signed char* a1p = A1 + aoff;
    const signed char* a2p = A2 + aoff;
    const signed char* b1p = B1 + boff;
    const signed char* b2p = B2 + boff;

    intx4 accM[4][4], accX[4][4];
    #pragma unroll
    for (int i = 0; i < 4; ++i)
        #pragma unroll
        for (int j = 0; j < 4; ++j) {
            accM[i][j] = intx4{0, 0, 0, 0};
            accX[i][j] = intx4{0, 0, 0, 0};
        }

    for (int t = 0; t < kiters; ++t) {
        const size_t d = (size_t)t << 6;      // k advance
        intx4 a1[4], b1[4], a2[4], b2[4];
        #pragma unroll
        for (int i = 0; i < 4; ++i) {
            a1[i] = *(const intx4*)(a1p + (size_t)i * 16 * 1024 + d);
            b1[i] = *(const intx4*)(b1p + (size_t)i * 16 * 1024 + d);
            a2[i] = *(const intx4*)(a2p + (size_t)i * 16 * 1024 + d);
            b2[i] = *(const intx4*)(b2p + (size_t)i * 16 * 1024 + d);
        }
        #pragma unroll
        for (int i = 0; i < 4; ++i)
            #pragma unroll
            for (int j = 0; j < 4; ++j)
                accM[i][j] = __builtin_amdgcn_mfma_i32_16x16x64_i8(a1[i], b1[j], accM[i][j], 0, 0, 0);
        #pragma unroll
        for (int i = 0; i < 4; ++i)
            #pragma unroll
            for (int j = 0; j < 4; ++j)
                accX[i][j] = __builtin_amdgcn_mfma_i32_16x16x64_i8(a2[i], b1[j], accX[i][j], 0, 0, 0);
        #pragma unroll
        for (int i = 0; i < 4; ++i)
            #pragma unroll
            for (int j = 0; j < 4; ++j)
                accX[i][j] = __builtin_amdgcn_mfma_i32_16x16x64_i8(a1[i], b2[j], accX[i][j], 0, 0, 0);
    }

    // Epilogue. C/D layout: col=lane&15, row=(lane>>4)*4+reg.
    #pragma unroll
    for (int j = 0; j < 4; ++j) {
        const int col = n0 + wn + j * 16 + r;
        const float bv = bias[col];
        #pragma unroll
        for (int i = 0; i < 4; ++i) {
            const int row0 = m0 + wm + i * 16 + q * 4;
            #pragma unroll
            for (int rr = 0; rr < 4; ++rr) {
                float pre = fmaf((float)accM[i][j][rr], 0x1p-16f,
                            fmaf((float)accX[i][j][rr], 0x1p-23f, bv));
                float o = tanh_fast(pre);
                signed char q1, q2;
                quant_h(o, q1, q2);
                const size_t idx = (size_t)(row0 + rr) * 1024 + col;
                C1[idx] = q1;
                C2[idx] = q2;
            }
        }
    }
}

// ---------------------------------------------------------------------------
// Final: out[row] = h3[row,:] . W_last + b_last; h3 = H1*2^-6 + H2*2^-13.
// ---------------------------------------------------------------------------
__global__ __launch_bounds__(256)
void final_kernel(const signed char* __restrict__ H1, const signed char* __restrict__ H2,
                  const float* __restrict__ Wl, const float* __restrict__ bl,
                  float* __restrict__ out) {
    const int lane = threadIdx.x & 63;
    const int wave = threadIdx.x >> 6;
    const int row  = blockIdx.x * 4 + wave;
    const size_t base = (size_t)row * 1024;
    float s = 0.0f;
    #pragma unroll
    for (int c = 0; c < 2; ++c) {
        const int e = c * 512 + lane * 8;
        i8x8 h1 = *(const i8x8*)(H1 + base + e);
        i8x8 h2 = *(const i8x8*)(H2 + base + e);
        floatx8 wv = *(const floatx8*)(Wl + e);
        #pragma unroll
        for (int j = 0; j < 8; ++j) {
            float h = fmaf((float)h2[j], 0x1p-13f, (float)h1[j] * 0x1p-6f);
            s = fmaf(h, wv[j], s);
        }
    }
    #pragma unroll
    for (int off = 32; off > 0; off >>= 1) s += __shfl_down(s, off);
    if (lane == 0) out[row] = s + bl[0];
}

// ---------------------------------------------------------------------------
extern "C" void kernel_launch(void* const* d_in, const int* in_sizes, int n_in,
                              void* d_out, int out_size, void* d_ws, size_t ws_size,
                              hipStream_t stream) {
    const float* X  = (const float*)d_in[0];
    const float* W0 = (const float*)d_in[1];
    const float* b0 = (const float*)d_in[2];
    const float* W1 = (const float*)d_in[3];
    const float* b1 = (const float*)d_in[4];
    const float* W2 = (const float*)d_in[5];
    const float* b2 = (const float*)d_in[6];
    const float* W3 = (const float*)d_in[7];
    const float* b3 = (const float*)d_in[8];
    const float* Wl = (const float*)d_in[9];
    const float* bl = (const float*)d_in[10];
    float* out = (float*)d_out;

    const int Nrows = in_sizes[0] / 2;                 // 65536
    const size_t WT = 1024 * 1024;                     // bytes per i8 weight plane
    const size_t wt_bytes = 6 * WT;                    // 6 MiB
    const size_t slack = 512;

    int R = 0;
    const int Rcap = Nrows < 32768 ? Nrows : 32768;
    for (int r = Rcap; r >= 128; r >>= 1)
        if ((size_t)4 * r * 1024 + wt_bytes + slack <= ws_size) { R = r; break; }
    if (!R) return;

    signed char* wsp  = (signed char*)d_ws;
    signed char* Wt1a = wsp;            signed char* Wt1b = Wt1a + WT;
    signed char* Wt2a = Wt1b + WT;      signed char* Wt2b = Wt2a + WT;
    signed char* Wt3a = Wt2b + WT;      signed char* Wt3b = Wt3a + WT;
    const size_t plane = (size_t)R * 1024;
    signed char* P0a = Wt3b + WT;       signed char* P0b = P0a + plane;
    signed char* P1a = P0b + plane;     signed char* P1b = P1a + plane;

    const dim3 tb(256);
    transposeQ<<<dim3(32, 32), tb, 0, stream>>>(W1, Wt1a, Wt1b);
    transposeQ<<<dim3(32, 32), tb, 0, stream>>>(W2, Wt2a, Wt2b);
    transposeQ<<<dim3(32, 32), tb, 0, stream>>>(W3, Wt3a, Wt3b);

    const int nchunks = Nrows / R;
    for (int c = 0; c < nchunks; ++c) {
        const float* Xc = X + (size_t)c * R * 2;
        float* outc = out + (size_t)c * R;

        layer0_kernel<<<R / 2, tb, 0, stream>>>(Xc, W0, b0, P0a, P0b);

        const dim3 gg(R / 128, 8);                    // m fast
        gemm_tanh_i8<<<gg, tb, 0, stream>>>(P0a, P0b, Wt1a, Wt1b, b1, P1a, P1b, 1024);
        gemm_tanh_i8<<<gg, tb, 0, stream>>>(P1a, P1b, Wt2a, Wt2b, b2, P0a, P0b, 512);
        gemm_tanh_i8<<<gg, tb, 0, stream>>>(P0a, P0b, Wt3a, Wt3b, b3, P1a, P1b, 256);

        final_kernel<<<R / 4, tb, 0, stream>>>(P1a, P1b, Wl, bl, outc);
    }
}

// Round 10
// 596.345 us; speedup vs baseline: 8.1316x; 2.3048x over previous
//
#include <hip/hip_runtime.h>
#include <cstdint>
#include <cstddef>

// ---------------------------------------------------------------------------
// BsPINN forward, single-fp16 MFMA (round 10).
// R9 post-mortem: LDS-free global fragments = latency-bound (12% MfmaUtil).
// R10: back to R6's green LDS structure + R8's reg-prefetch pipeline (its
// fault was ONLY the launch_bounds spill), and the big lever: fp16 single
// precision. Error model calibrated on R6's measured 4.88e-4 (h rms ~0.044,
// zero biases) says fp16 quantization of h and w gives output absmax
// ~1.5e-4 << 9.2e-4 threshold. 1 MFMA per K=32 frag (was 3), 2 staged
// planes (was 4), acc 64 VGPR (was 128).
//   h0 = tanh(norm(X) @ W0 + b0)        K=2   fp32 vector
//   h1 = tanh(h0 @ W1 + b1)             K=1024 MFMA f16
//   h2 = tanh(h1 @ (W2*m2) + b2)        2 x 512 block-diag (K=512)
//   h3 = tanh(h2 @ (W3*m3) + b3)        4 x 256 block-diag (K=256)
//   out = h3 @ W_last + b_last          fp32 wave dot
// ---------------------------------------------------------------------------

typedef _Float16  f16x8   __attribute__((ext_vector_type(8)));
typedef float     floatx4 __attribute__((ext_vector_type(4)));
typedef float     floatx8 __attribute__((ext_vector_type(8)));

__device__ __forceinline__ float tanh_fast(float x) {
    float e = __expf(2.0f * x);
    return 1.0f - 2.0f / (e + 1.0f);
}

// ---------------------------------------------------------------------------
// Weight transpose + f16 convert: fp32 W[K=1024][N=1024] -> f16 Wt[N][K].
// ---------------------------------------------------------------------------
__global__ __launch_bounds__(256)
void transposeH(const float* __restrict__ W, _Float16* __restrict__ Wt) {
    __shared__ float tile[32][33];
    const int tx = threadIdx.x & 31;
    const int ty = threadIdx.x >> 5;     // 0..7
    #pragma unroll
    for (int j = 0; j < 4; ++j) {
        int r = ty + j * 8;
        tile[r][tx] = W[(size_t)(blockIdx.y * 32 + r) * 1024 + blockIdx.x * 32 + tx];
    }
    __syncthreads();
    #pragma unroll
    for (int j = 0; j < 4; ++j) {
        int r = ty + j * 8;
        Wt[(size_t)(blockIdx.x * 32 + r) * 1024 + blockIdx.y * 32 + tx] =
            (_Float16)tile[tx][r];
    }
}

// ---------------------------------------------------------------------------
// Layer 0 (fp32 in): h0 = tanh(xa*W0[0][:] + xb*W0[1][:] + b0) -> f16.
// xa = x0/pi - 1, xb = 2*x1 - 1. One thread = 8 output cols of one row.
// ---------------------------------------------------------------------------
__global__ __launch_bounds__(256)
void layer0_kernel(const float* __restrict__ X, const float* __restrict__ W0,
                   const float* __restrict__ b0, _Float16* __restrict__ H) {
    const int idx = blockIdx.x * 256 + threadIdx.x;
    const int row = idx >> 7;
    const int j0  = (idx & 127) << 3;
    const float x0 = X[row * 2 + 0];
    const float x1 = X[row * 2 + 1];
    const float xa = x0 * 0.31830988618379067f - 1.0f;   // x0/pi - 1
    const float xb = 2.0f * x1 - 1.0f;
    floatx8 wa = *(const floatx8*)(W0 + j0);
    floatx8 wb = *(const floatx8*)(W0 + 1024 + j0);
    floatx8 bb = *(const floatx8*)(b0 + j0);
    f16x8 o;
    #pragma unroll
    for (int j = 0; j < 8; ++j) {
        float v = fmaf(xa, wa[j], fmaf(xb, wb[j], bb[j]));
        o[j] = (_Float16)tanh_fast(v);
    }
    *(f16x8*)(H + (size_t)row * 1024 + j0) = o;
}

// ---------------------------------------------------------------------------
// GEMM + bias + tanh, single f16. C = tanh(A @ Wt^T + bias) as f16.
// A [rows][1024] f16; Wt [N][K] f16. KB = diag block (1024/512/256):
// output cols [n0,n0+128) need only k in [(n0/KB)*KB, +KB).
// 128x128 tile, BK=32, 4 waves (2x2), 4x4 16x16x32 frags, 1 MFMA/frag/kiter.
// Pipeline: prefetch k-tile t+1 into regs during MFMA of tile t (R8
// structure, NO launch_bounds cap -> no spill).
// ---------------------------------------------------------------------------
__global__ __launch_bounds__(256)
void gemm_tanh_f16(const _Float16* __restrict__ A, const _Float16* __restrict__ Bt,
                   const float* __restrict__ bias, _Float16* __restrict__ C, int KB) {
    __shared__ _Float16 As[128 * 32];   // 8 KB
    __shared__ _Float16 Bs[128 * 32];   // 8 KB

    const int tid  = threadIdx.x;
    const int lane = tid & 63;
    const int wave = tid >> 6;
    const int m0 = blockIdx.x * 128;          // m fast (proven cache order)
    const int n0 = blockIdx.y * 128;
    const int kbeg   = (n0 / KB) * KB;
    const int kiters = KB >> 5;
    const int wm = (wave & 1) << 6;
    const int wn = (wave >> 1) << 6;
    const int r = lane & 15;
    const int q = lane >> 4;

    // Staging geometry: 512 16B slots per tensor (8 f16 each), 2 per thread.
    const int rowS0 = tid >> 2;               // slot tid     -> rows 0..63
    const int rowS1 = 64 + rowS0;             // slot 256+tid -> rows 64..127
    const int seg   = (tid & 3) << 3;         // 8-elem segment in 32-k row
    const size_t gA0 = (size_t)(m0 + rowS0) * 1024 + kbeg + seg;
    const size_t gA1 = (size_t)(m0 + rowS1) * 1024 + kbeg + seg;
    const size_t gB0 = (size_t)(n0 + rowS0) * 1024 + kbeg + seg;
    const size_t gB1 = (size_t)(n0 + rowS1) * 1024 + kbeg + seg;
    const int ldsE0 = tid * 8;                // elem offsets
    const int ldsE1 = (256 + tid) * 8;

    floatx4 acc[4][4];
    #pragma unroll
    for (int i = 0; i < 4; ++i)
        #pragma unroll
        for (int j = 0; j < 4; ++j)
            acc[i][j] = floatx4{0.f, 0.f, 0.f, 0.f};

    // Prologue: k-tile 0 into regs.
    f16x8 va[2], vb[2];
    va[0] = *(const f16x8*)(A + gA0);   va[1] = *(const f16x8*)(A + gA1);
    vb[0] = *(const f16x8*)(Bt + gB0);  vb[1] = *(const f16x8*)(Bt + gB1);

    for (int t = 0; t < kiters; ++t) {
        __syncthreads();                      // prior iter's ds_reads done
        *(f16x8*)(As + ldsE0) = va[0];  *(f16x8*)(As + ldsE1) = va[1];
        *(f16x8*)(Bs + ldsE0) = vb[0];  *(f16x8*)(Bs + ldsE1) = vb[1];
        __syncthreads();                      // tile t visible

        if (t + 1 < kiters) {                 // prefetch t+1 (overlaps MFMA)
            const size_t d = (size_t)(t + 1) << 5;
            va[0] = *(const f16x8*)(A + gA0 + d);   va[1] = *(const f16x8*)(A + gA1 + d);
            vb[0] = *(const f16x8*)(Bt + gB0 + d);  vb[1] = *(const f16x8*)(Bt + gB1 + d);
        }

        f16x8 af[4], bf[4];
        #pragma unroll
        for (int i = 0; i < 4; ++i) {
            af[i] = *(const f16x8*)(As + (wm + i * 16 + r) * 32 + q * 8);
            bf[i] = *(const f16x8*)(Bs + (wn + i * 16 + r) * 32 + q * 8);
        }
        #pragma unroll
        for (int i = 0; i < 4; ++i)
            #pragma unroll
            for (int j = 0; j < 4; ++j)
                acc[i][j] = __builtin_amdgcn_mfma_f32_16x16x32_f16(af[i], bf[j], acc[i][j], 0, 0, 0);
    }

    // Epilogue. C/D layout: col=lane&15, row=(lane>>4)*4+reg.
    #pragma unroll
    for (int j = 0; j < 4; ++j) {
        const int col = n0 + wn + j * 16 + r;
        const float bv = bias[col];
        #pragma unroll
        for (int i = 0; i < 4; ++i) {
            const int row0 = m0 + wm + i * 16 + q * 4;
            #pragma unroll
            for (int rr = 0; rr < 4; ++rr) {
                float o = tanh_fast(acc[i][j][rr] + bv);
                C[(size_t)(row0 + rr) * 1024 + col] = (_Float16)o;
            }
        }
    }
}

// ---------------------------------------------------------------------------
// Final: out[row] = h3[row,:] . W_last + b_last. One wave per row; fp32 out.
// ---------------------------------------------------------------------------
__global__ __launch_bounds__(256)
void final_kernel(const _Float16* __restrict__ H,
                  const float* __restrict__ Wl, const float* __restrict__ bl,
                  float* __restrict__ out) {
    const int lane = threadIdx.x & 63;
    const int wave = threadIdx.x >> 6;
    const int row  = blockIdx.x * 4 + wave;
    const size_t base = (size_t)row * 1024;
    float s = 0.0f;
    #pragma unroll
    for (int c = 0; c < 2; ++c) {
        const int e = c * 512 + lane * 8;
        f16x8 hv = *(const f16x8*)(H + base + e);
        floatx8 wv = *(const floatx8*)(Wl + e);
        #pragma unroll
        for (int j = 0; j < 8; ++j)
            s = fmaf((float)hv[j], wv[j], s);
    }
    #pragma unroll
    for (int off = 32; off > 0; off >>= 1) s += __shfl_down(s, off);
    if (lane == 0) out[row] = s + bl[0];
}

// ---------------------------------------------------------------------------
extern "C" void kernel_launch(void* const* d_in, const int* in_sizes, int n_in,
                              void* d_out, int out_size, void* d_ws, size_t ws_size,
                              hipStream_t stream) {
    const float* X  = (const float*)d_in[0];
    const float* W0 = (const float*)d_in[1];
    const float* b0 = (const float*)d_in[2];
    const float* W1 = (const float*)d_in[3];
    const float* b1 = (const float*)d_in[4];
    const float* W2 = (const float*)d_in[5];
    const float* b2 = (const float*)d_in[6];
    const float* W3 = (const float*)d_in[7];
    const float* b3 = (const float*)d_in[8];
    const float* Wl = (const float*)d_in[9];
    const float* bl = (const float*)d_in[10];
    float* out = (float*)d_out;

    const int Nrows = in_sizes[0] / 2;                 // 65536
    const size_t WT = 1024 * 1024;                     // elems per f16 weight plane
    const size_t wt_bytes = 3 * WT * 2;                // 6 MiB
    const size_t slack = 512;

    // chunk rows R (pow2): 2 f16 activation planes (R*2048 B each) must fit.
    int R = 0;
    const int Rcap = Nrows < 32768 ? Nrows : 32768;
    for (int r = Rcap; r >= 128; r >>= 1)
        if ((size_t)2 * r * 2048 + wt_bytes + slack <= ws_size) { R = r; break; }
    if (!R) return;

    _Float16* wsp = (_Float16*)d_ws;
    _Float16* Wt1 = wsp;
    _Float16* Wt2 = Wt1 + WT;
    _Float16* Wt3 = Wt2 + WT;
    const size_t plane = (size_t)R * 1024;
    _Float16* P0 = Wt3 + WT;
    _Float16* P1 = P0 + plane;

    const dim3 tb(256);
    transposeH<<<dim3(32, 32), tb, 0, stream>>>(W1, Wt1);
    transposeH<<<dim3(32, 32), tb, 0, stream>>>(W2, Wt2);
    transposeH<<<dim3(32, 32), tb, 0, stream>>>(W3, Wt3);

    const int nchunks = Nrows / R;
    for (int c = 0; c < nchunks; ++c) {
        const float* Xc = X + (size_t)c * R * 2;
        float* outc = out + (size_t)c * R;

        layer0_kernel<<<R / 2, tb, 0, stream>>>(Xc, W0, b0, P0);

        const dim3 gg(R / 128, 8);                    // m fast
        gemm_tanh_f16<<<gg, tb, 0, stream>>>(P0, Wt1, b1, P1, 1024);
        gemm_tanh_f16<<<gg, tb, 0, stream>>>(P1, Wt2, b2, P0, 512);
        gemm_tanh_f16<<<gg, tb, 0, stream>>>(P0, Wt3, b3, P1, 256);

        final_kernel<<<R / 4, tb, 0, stream>>>(P1, Wl, bl, outc);
    }
}

// Round 11
// 496.027 us; speedup vs baseline: 9.7762x; 1.2022x over previous
//
#include <hip/hip_runtime.h>
#include <cstdint>
#include <cstddef>

// ---------------------------------------------------------------------------
// BsPINN forward, single-fp16 MFMA (round 11).
// R10 green: 596us, absmax 2.44e-4, layer1 613 TF (MfmaUtil 27%, occ 27%).
// R11: (a) 256x128 tile / 512 threads / 8 waves -> grid halves (full
// residency), A-traffic per n-pass halves, 2x waves per barrier window;
// (b) final dot fused into layer3 epilogue (h3 never hits memory; one fp32
// atomic per row/wave/n-block after 16-lane shfl reduce).
//   h0 = tanh(norm(X) @ W0 + b0)        K=2   fp32 vector
//   h1 = tanh(h0 @ W1 + b1)             K=1024 MFMA f16
//   h2 = tanh(h1 @ (W2*m2) + b2)        2 x 512 block-diag (K=512)
//   out = tanh(h2 @ (W3*m3) + b3) @ W_last + b_last   (fused, K=256)
// fp16 error model validated R10 (2.44e-4 << 9.2e-4 threshold).
// ---------------------------------------------------------------------------

typedef _Float16  f16x8   __attribute__((ext_vector_type(8)));
typedef float     floatx4 __attribute__((ext_vector_type(4)));
typedef float     floatx8 __attribute__((ext_vector_type(8)));

__device__ __forceinline__ float tanh_fast(float x) {
    float e = __expf(2.0f * x);
    return 1.0f - 2.0f / (e + 1.0f);
}

// ---------------------------------------------------------------------------
// Weight transpose + f16 convert: fp32 W[K=1024][N=1024] -> f16 Wt[N][K].
// ---------------------------------------------------------------------------
__global__ __launch_bounds__(256)
void transposeH(const float* __restrict__ W, _Float16* __restrict__ Wt) {
    __shared__ float tile[32][33];
    const int tx = threadIdx.x & 31;
    const int ty = threadIdx.x >> 5;     // 0..7
    #pragma unroll
    for (int j = 0; j < 4; ++j) {
        int r = ty + j * 8;
        tile[r][tx] = W[(size_t)(blockIdx.y * 32 + r) * 1024 + blockIdx.x * 32 + tx];
    }
    __syncthreads();
    #pragma unroll
    for (int j = 0; j < 4; ++j) {
        int r = ty + j * 8;
        Wt[(size_t)(blockIdx.x * 32 + r) * 1024 + blockIdx.y * 32 + tx] =
            (_Float16)tile[tx][r];
    }
}

// ---------------------------------------------------------------------------
// out[row] := b_last (fp32) — re-initialized every call before layer3 atomics.
// ---------------------------------------------------------------------------
__global__ __launch_bounds__(256)
void init_out(float* __restrict__ out, const float* __restrict__ bl) {
    out[blockIdx.x * 256 + threadIdx.x] = bl[0];
}

// ---------------------------------------------------------------------------
// Layer 0 (fp32 in): h0 = tanh(xa*W0[0][:] + xb*W0[1][:] + b0) -> f16.
// ---------------------------------------------------------------------------
__global__ __launch_bounds__(256)
void layer0_kernel(const float* __restrict__ X, const float* __restrict__ W0,
                   const float* __restrict__ b0, _Float16* __restrict__ H) {
    const int idx = blockIdx.x * 256 + threadIdx.x;
    const int row = idx >> 7;
    const int j0  = (idx & 127) << 3;
    const float x0 = X[row * 2 + 0];
    const float x1 = X[row * 2 + 1];
    const float xa = x0 * 0.31830988618379067f - 1.0f;   // x0/pi - 1
    const float xb = 2.0f * x1 - 1.0f;
    floatx8 wa = *(const floatx8*)(W0 + j0);
    floatx8 wb = *(const floatx8*)(W0 + 1024 + j0);
    floatx8 bb = *(const floatx8*)(b0 + j0);
    f16x8 o;
    #pragma unroll
    for (int j = 0; j < 8; ++j) {
        float v = fmaf(xa, wa[j], fmaf(xb, wb[j], bb[j]));
        o[j] = (_Float16)tanh_fast(v);
    }
    *(f16x8*)(H + (size_t)row * 1024 + j0) = o;
}

// ---------------------------------------------------------------------------
// GEMM + bias + tanh, f16. 256x128 tile, 512 threads = 8 waves (4m x 2n),
// each wave 64x64 via 4x4 16x16x32 frags. BK=32, two-barrier K-loop with
// register prefetch of tile t+1. KB = diag block: cols [n0,n0+128) need
// k in [(n0/KB)*KB, +KB).
// FUSE: instead of storing C, epilogue computes per-row partial of
// tanh(pre) . Wl over this block's 64 cols (per wave), shfl-reduces across
// the 16 r-lanes, and atomicAdds into out[row] (pre-initialized to b_last).
// ---------------------------------------------------------------------------
template <bool FUSE>
__global__ __launch_bounds__(512)
void gemm_tanh_f16(const _Float16* __restrict__ A, const _Float16* __restrict__ Bt,
                   const float* __restrict__ bias, _Float16* __restrict__ C,
                   const float* __restrict__ Wl, float* __restrict__ out, int KB) {
    __shared__ _Float16 As[256 * 32];   // 16 KB
    __shared__ _Float16 Bs[128 * 32];   // 8 KB

    const int tid  = threadIdx.x;
    const int lane = tid & 63;
    const int wave = tid >> 6;
    const int m0 = blockIdx.x * 256;          // m fast (proven cache order)
    const int n0 = blockIdx.y * 128;
    const int kbeg   = (n0 / KB) * KB;
    const int kiters = KB >> 5;
    const int wm = (wave & 3) << 6;           // 0,64,128,192
    const int wn = (wave >> 2) << 6;          // 0,64
    const int r = lane & 15;
    const int q = lane >> 4;

    // Staging: A = 1024 16B slots (2/thread), B = 512 slots (1/thread).
    const int rowA0 = tid >> 2;               // 0..127
    const int rowA1 = 128 + rowA0;            // 128..255
    const int seg   = (tid & 3) << 3;         // 8-elem segment of 32-k row
    const size_t gA0 = (size_t)(m0 + rowA0) * 1024 + kbeg + seg;
    const size_t gA1 = (size_t)(m0 + rowA1) * 1024 + kbeg + seg;
    const size_t gB  = (size_t)(n0 + rowA0) * 1024 + kbeg + seg;  // rowB==rowA0
    const int ldsA0 = tid * 8;
    const int ldsA1 = (512 + tid) * 8;
    const int ldsB  = tid * 8;

    floatx4 acc[4][4];
    #pragma unroll
    for (int i = 0; i < 4; ++i)
        #pragma unroll
        for (int j = 0; j < 4; ++j)
            acc[i][j] = floatx4{0.f, 0.f, 0.f, 0.f};

    // Prologue: k-tile 0 into regs.
    f16x8 va0 = *(const f16x8*)(A + gA0);
    f16x8 va1 = *(const f16x8*)(A + gA1);
    f16x8 vb  = *(const f16x8*)(Bt + gB);

    for (int t = 0; t < kiters; ++t) {
        __syncthreads();                      // prior iter's ds_reads done
        *(f16x8*)(As + ldsA0) = va0;
        *(f16x8*)(As + ldsA1) = va1;
        *(f16x8*)(Bs + ldsB)  = vb;
        __syncthreads();                      // tile t visible

        if (t + 1 < kiters) {                 // prefetch t+1 (overlaps MFMA)
            const size_t d = (size_t)(t + 1) << 5;
            va0 = *(const f16x8*)(A + gA0 + d);
            va1 = *(const f16x8*)(A + gA1 + d);
            vb  = *(const f16x8*)(Bt + gB + d);
        }

        f16x8 af[4], bf[4];
        #pragma unroll
        for (int i = 0; i < 4; ++i) {
            af[i] = *(const f16x8*)(As + (wm + i * 16 + r) * 32 + q * 8);
            bf[i] = *(const f16x8*)(Bs + (wn + i * 16 + r) * 32 + q * 8);
        }
        #pragma unroll
        for (int i = 0; i < 4; ++i)
            #pragma unroll
            for (int j = 0; j < 4; ++j)
                acc[i][j] = __builtin_amdgcn_mfma_f32_16x16x32_f16(af[i], bf[j], acc[i][j], 0, 0, 0);
    }

    // Epilogue. C/D layout: col=lane&15 (within 16), row=(lane>>4)*4+reg.
    float bv[4], wlv[4];
    #pragma unroll
    for (int j = 0; j < 4; ++j) {
        const int col = n0 + wn + j * 16 + r;
        bv[j] = bias[col];
        if (FUSE) wlv[j] = Wl[col];
    }
    #pragma unroll
    for (int i = 0; i < 4; ++i) {
        const int row0 = m0 + wm + i * 16 + q * 4;
        #pragma unroll
        for (int rr = 0; rr < 4; ++rr) {
            if (!FUSE) {
                #pragma unroll
                for (int j = 0; j < 4; ++j) {
                    float o = tanh_fast(acc[i][j][rr] + bv[j]);
                    const int col = n0 + wn + j * 16 + r;
                    C[(size_t)(row0 + rr) * 1024 + col] = (_Float16)o;
                }
            } else {
                float p = 0.f;
                #pragma unroll
                for (int j = 0; j < 4; ++j)
                    p = fmaf(tanh_fast(acc[i][j][rr] + bv[j]), wlv[j], p);
                // reduce across the 16 r-lanes (lane = q*16 + r)
                p += __shfl_down(p, 8);
                p += __shfl_down(p, 4);
                p += __shfl_down(p, 2);
                p += __shfl_down(p, 1);
                if (r == 0) atomicAdd(out + row0 + rr, p);
            }
        }
    }
}

// ---------------------------------------------------------------------------
extern "C" void kernel_launch(void* const* d_in, const int* in_sizes, int n_in,
                              void* d_out, int out_size, void* d_ws, size_t ws_size,
                              hipStream_t stream) {
    const float* X  = (const float*)d_in[0];
    const float* W0 = (const float*)d_in[1];
    const float* b0 = (const float*)d_in[2];
    const float* W1 = (const float*)d_in[3];
    const float* b1 = (const float*)d_in[4];
    const float* W2 = (const float*)d_in[5];
    const float* b2 = (const float*)d_in[6];
    const float* W3 = (const float*)d_in[7];
    const float* b3 = (const float*)d_in[8];
    const float* Wl = (const float*)d_in[9];
    const float* bl = (const float*)d_in[10];
    float* out = (float*)d_out;

    const int Nrows = in_sizes[0] / 2;                 // 65536
    const size_t WT = 1024 * 1024;                     // elems per f16 weight plane
    const size_t wt_bytes = 3 * WT * 2;                // 6 MiB
    const size_t slack = 512;

    // chunk rows R (pow2, multiple of 256): 2 f16 planes must fit ws.
    int R = 0;
    const int Rcap = Nrows < 32768 ? Nrows : 32768;
    for (int r = Rcap; r >= 256; r >>= 1)
        if ((size_t)2 * r * 2048 + wt_bytes + slack <= ws_size) { R = r; break; }
    if (!R) return;

    _Float16* wsp = (_Float16*)d_ws;
    _Float16* Wt1 = wsp;
    _Float16* Wt2 = Wt1 + WT;
    _Float16* Wt3 = Wt2 + WT;
    const size_t plane = (size_t)R * 1024;
    _Float16* P0 = Wt3 + WT;
    _Float16* P1 = P0 + plane;

    const dim3 tb(256);
    transposeH<<<dim3(32, 32), tb, 0, stream>>>(W1, Wt1);
    transposeH<<<dim3(32, 32), tb, 0, stream>>>(W2, Wt2);
    transposeH<<<dim3(32, 32), tb, 0, stream>>>(W3, Wt3);
    init_out<<<Nrows / 256, tb, 0, stream>>>(out, bl);

    const int nchunks = Nrows / R;
    for (int c = 0; c < nchunks; ++c) {
        const float* Xc = X + (size_t)c * R * 2;
        float* outc = out + (size_t)c * R;

        layer0_kernel<<<R / 2, tb, 0, stream>>>(Xc, W0, b0, P0);

        const dim3 tg(512);
        const dim3 gg(R / 256, 8);                    // m fast
        gemm_tanh_f16<false><<<gg, tg, 0, stream>>>(P0, Wt1, b1, P1, nullptr, nullptr, 1024);
        gemm_tanh_f16<false><<<gg, tg, 0, stream>>>(P1, Wt2, b2, P0, nullptr, nullptr, 512);
        gemm_tanh_f16<true ><<<gg, tg, 0, stream>>>(P0, Wt3, b3, nullptr, Wl, outc, 256);
    }
}